// Round 10
// baseline (82.471 us; speedup 1.0000x reference)
//
#include <hip/hip_runtime.h>
#include <hip/hip_bf16.h>

// out[e] = concat(h[i0], h[i1]) @ W + b, h = logmap0(x)
// Rewritten: y[n][0:4] = h[n]·W[0:128,:] + b   (b folded here)
//            y[n][4:8] = h[n]·W[128:256,:]
//            out[e][c] = y[i0][c] + y[i1][4+c]
//
// Preferred path: single fused kernel, manual device-scope grid barrier.
//   512 blocks @ launch_bounds(256,4) -> capacity 4 blocks/CU, need 2 -> all
//   co-resident, spin barrier cannot deadlock; spin is bounded regardless.
//   Barrier counter at ws_size-64 (bounds-checked!), zeroed by hipMemsetAsync.
// Fallback path (ws too small for counter): two dispatches (R6 structure).

#define DIM 128
#define NBLOCKS 512

typedef float f32x4 __attribute__((ext_vector_type(4)));
typedef int   i32x2 __attribute__((ext_vector_type(2)));

// ---- shared node-phase body ----
__device__ __forceinline__ void node_phase(
    const float* __restrict__ x, const float* __restrict__ b,
    float* __restrict__ y, const float* wl, int li, int gid,
    int wave, int total_waves, int n_nodes)
{
    for (int base = wave * 32; base < n_nodes; base += total_waves * 32) {
        const int n0 = base + gid * 2;
        if (n0 >= n_nodes) continue;
        const bool has1 = (n0 + 1) < n_nodes;
        const int  n1   = has1 ? (n0 + 1) : n0;

        const f32x4* xp0 = (const f32x4*)(x + (size_t)n0 * DIM + li * 4);
        const f32x4* xp1 = (const f32x4*)(x + (size_t)n1 * DIM + li * 4);

        f32x4 A[8], B[8];
#pragma unroll
        for (int j = 0; j < 8; ++j) A[j] = xp0[j * 4];
#pragma unroll
        for (int j = 0; j < 8; ++j) B[j] = xp1[j * 4];

        float acc0[9], acc1[9];
#pragma unroll
        for (int i = 0; i < 9; ++i) { acc0[i] = 0.f; acc1[i] = 0.f; }

#pragma unroll
        for (int j = 0; j < 8; ++j) {
#pragma unroll
            for (int k = 0; k < 4; ++k) {
                // d = j*16+li*4+k ; float-offset = li*36 + j*144 + k*8
                const f32x4 wa = *(const f32x4*)(wl + j * 144 + k * 8);
                const f32x4 wb = *(const f32x4*)(wl + j * 144 + k * 8 + 4);
                const float a = A[j][k], bb = B[j][k];
                acc0[0] += a * a;        acc1[0] += bb * bb;
                acc0[1] += a * wa[0];    acc1[1] += bb * wa[0];
                acc0[2] += a * wa[1];    acc1[2] += bb * wa[1];
                acc0[3] += a * wa[2];    acc1[3] += bb * wa[2];
                acc0[4] += a * wa[3];    acc1[4] += bb * wa[3];
                acc0[5] += a * wb[0];    acc1[5] += bb * wb[0];
                acc0[6] += a * wb[1];    acc1[6] += bb * wb[1];
                acc0[7] += a * wb[2];    acc1[7] += bb * wb[2];
                acc0[8] += a * wb[3];    acc1[8] += bb * wb[3];
            }
        }

#pragma unroll
        for (int i = 0; i < 9; ++i) {
            acc0[i] += __shfl_xor(acc0[i], 1, 64);
            acc0[i] += __shfl_xor(acc0[i], 2, 64);
            acc1[i] += __shfl_xor(acc1[i], 1, 64);
            acc1[i] += __shfl_xor(acc1[i], 2, 64);
        }

        const bool second = (li & 1);
        const bool nodeB  = (li >= 2);

        const float sq = nodeB ? acc1[0] : acc0[0];
        const float w0 = second ? (nodeB ? acc1[5] : acc0[5]) : (nodeB ? acc1[1] : acc0[1]);
        const float w1 = second ? (nodeB ? acc1[6] : acc0[6]) : (nodeB ? acc1[2] : acc0[2]);
        const float w2 = second ? (nodeB ? acc1[7] : acc0[7]) : (nodeB ? acc1[3] : acc0[3]);
        const float w3 = second ? (nodeB ? acc1[8] : acc0[8]) : (nodeB ? acc1[4] : acc0[4]);

        float norm = fmaxf(sqrtf(sq), 1e-15f);               // MIN_NORM
        const float aa  = fminf(norm, 1.0f - 1e-6f);         // ATANH_EPS clip
        const float art = 0.5f * log1pf(2.0f * aa / (1.0f - aa));  // artanh
        const float scale = art / norm;

        const f32x4 bv4 = *(const f32x4*)b;
        f32x4 o;
        o[0] = w0 * scale + (second ? 0.f : bv4[0]);
        o[1] = w1 * scale + (second ? 0.f : bv4[1]);
        o[2] = w2 * scale + (second ? 0.f : bv4[2]);
        o[3] = w3 * scale + (second ? 0.f : bv4[3]);

        if (!(nodeB && !has1))
            *(f32x4*)(y + (size_t)n0 * 8 + li * 4) = o;
    }
}

__device__ __forceinline__ void load_w_lds(float* wp, const float* __restrict__ W, int t)
{
    const int r = t & 127, h = t >> 7;            // row, half
    const f32x4 wv = ((const f32x4*)W)[t];        // W[256][4], row t
    *(f32x4*)(wp + r * 8 + (r >> 2) * 4 + h * 4) = wv;
}

// ---------------- fused (preferred) ----------------
__global__ __launch_bounds__(256, 4) void fused_kernel(
    const float* __restrict__ x, const int* __restrict__ idx,
    const float* __restrict__ W, const float* __restrict__ b,
    float* __restrict__ y, float* __restrict__ out,
    unsigned int* __restrict__ barrier_ctr,
    int n_nodes, int n_edges)
{
    __shared__ float wp[1152];
    const int t = threadIdx.x;
    load_w_lds(wp, W, t);
    __syncthreads();

    const int lane = t & 63;
    const int li   = lane & 3;
    const int gid  = lane >> 2;
    const int wave = blockIdx.x * (blockDim.x >> 6) + (t >> 6);
    const int total_waves = gridDim.x * (blockDim.x >> 6);

    node_phase(x, b, y, wp + li * 36, li, gid, wave, total_waves, n_nodes);

    // ---- grid barrier: bounded spin, device-scope fences ----
    __syncthreads();
    if (t == 0) {
        __threadfence();                       // release y stores (agent scope)
        __hip_atomic_fetch_add(barrier_ctr, 1u, __ATOMIC_RELAXED,
                               __HIP_MEMORY_SCOPE_AGENT);
        unsigned int v; int spins = 0;
        do {
            v = __hip_atomic_load(barrier_ctr, __ATOMIC_RELAXED,
                                  __HIP_MEMORY_SCOPE_AGENT);
            if (v >= (unsigned int)gridDim.x) break;
            __builtin_amdgcn_s_sleep(2);
        } while (++spins < (1 << 20));          // ~50 ms cap: no wedge possible
        __threadfence();                       // acquire side
    }
    __syncthreads();

    // ---- edge phase (grid-stride) ----
    const int nthreads = gridDim.x * blockDim.x;
    const i32x2* idx2 = (const i32x2*)idx;
    for (int e = blockIdx.x * blockDim.x + t; e < n_edges; e += nthreads) {
        const i32x2 ii = __builtin_nontemporal_load(idx2 + e);
        const f32x4 a0 = *(const f32x4*)(y + (size_t)ii[0] * 8);
        const f32x4 c0 = *(const f32x4*)(y + (size_t)ii[1] * 8 + 4);
        const f32x4 o0 = a0 + c0;
        __builtin_nontemporal_store(o0, (f32x4*)out + e);
    }
}

// ---------------- fallback: two dispatches (R6 structure) ----------------
__global__ __launch_bounds__(256) void node_proj_kernel(
    const float* __restrict__ x, const float* __restrict__ W,
    const float* __restrict__ b, float* __restrict__ y, int n_nodes)
{
    __shared__ float wp[1152];
    const int t = threadIdx.x;
    load_w_lds(wp, W, t);
    __syncthreads();

    const int lane = t & 63;
    const int li   = lane & 3;
    const int gid  = lane >> 2;
    const int wave = blockIdx.x * (blockDim.x >> 6) + (t >> 6);
    const int total_waves = gridDim.x * (blockDim.x >> 6);
    node_phase(x, b, y, wp + li * 36, li, gid, wave, total_waves, n_nodes);
}

__global__ __launch_bounds__(256) void edge_kernel(
    const int* __restrict__ idx, const float* __restrict__ y,
    float* __restrict__ out, int n_edges)
{
    const int nthreads = gridDim.x * blockDim.x;
    const i32x2* idx2 = (const i32x2*)idx;
    for (int e = blockIdx.x * blockDim.x + threadIdx.x; e < n_edges; e += nthreads) {
        const i32x2 ii = __builtin_nontemporal_load(idx2 + e);
        const f32x4 a0 = *(const f32x4*)(y + (size_t)ii[0] * 8);
        const f32x4 c0 = *(const f32x4*)(y + (size_t)ii[1] * 8 + 4);
        const f32x4 o0 = a0 + c0;
        __builtin_nontemporal_store(o0, (f32x4*)out + e);
    }
}

extern "C" void kernel_launch(void* const* d_in, const int* in_sizes, int n_in,
                              void* d_out, int out_size, void* d_ws, size_t ws_size,
                              hipStream_t stream) {
    const float* x   = (const float*)d_in[0];
    const int*   idx = (const int*)d_in[1];
    const float* W   = (const float*)d_in[2];
    const float* b   = (const float*)d_in[3];
    float* out = (float*)d_out;

    const int n_nodes = in_sizes[0] / DIM;
    const int n_edges = in_sizes[1] / 2;

    float* y = (float*)d_ws;                       // n_nodes*8 floats = 3.2 MB
    const size_t y_bytes = (size_t)n_nodes * 8 * sizeof(float);

    if (ws_size >= y_bytes + 1024) {
        // counter at the END of ws, 64B-aligned: provably in-bounds.
        unsigned int* ctr =
            (unsigned int*)((char*)d_ws + ((ws_size - 64) & ~(size_t)63));
        (void)hipMemsetAsync(ctr, 0, sizeof(unsigned int), stream);
        fused_kernel<<<NBLOCKS, 256, 0, stream>>>(x, idx, W, b, y, out, ctr,
                                                  n_nodes, n_edges);
    } else {
        // fallback: two dispatches, no barrier needed (stream-ordered).
        const int blocks1 = (n_nodes + 127) / 128;
        node_proj_kernel<<<blocks1, 256, 0, stream>>>(x, W, b, y, n_nodes);
        const int blocks2 = 2048;
        edge_kernel<<<blocks2, 256, 0, stream>>>(idx, y, out, n_edges);
    }
}

// Round 11
// 31.665 us; speedup vs baseline: 2.6045x; 2.6045x over previous
//
#include <hip/hip_runtime.h>
#include <hip/hip_bf16.h>

// out[e] = concat(h[i0], h[i1]) @ W + b, h = logmap0(x)
// Rewritten: y[n][0:4] = h[n]·W[0:128,:] + b   (b folded here)
//            y[n][4:8] = h[n]·W[128:256,:]
//            out[e][c] = y[i0][c] + y[i1][4+c]
// Two dispatches (fusion measured WORSE: R10 82µs vs 33µs — edge phase is
// gather-latency-bound and needs max thread count, which fusion capped).

#define DIM 128

typedef float f32x4 __attribute__((ext_vector_type(4)));
typedef int   i32x2 __attribute__((ext_vector_type(2)));

// 4 lanes per node, 2 nodes per lane-group (32 nodes/wave), single-shot.
// Lane li of a group owns dims {j*16 + li*4 + k : j=0..7, k=0..3}.
// W packed in LDS: Wp[d] = {W[d][0:4], W[d+128][0:4]} at float-offset
// d*8 + (d>>2)*4 (skew every 4 rows -> conflict-free 4-address reads).
// Loads interleaved per-j (R2 codegen: lowest VGPR, best measured).
__global__ __launch_bounds__(256) void node_proj_kernel(
    const float* __restrict__ x, const float* __restrict__ W,
    const float* __restrict__ b, float* __restrict__ y, int n_nodes)
{
    __shared__ float wp[1152];
    const int t = threadIdx.x;
    {
        const int r = t & 127, h = t >> 7;            // row, half
        const f32x4 wv = ((const f32x4*)W)[t];        // W[256][4], row t
        *(f32x4*)(wp + r * 8 + (r >> 2) * 4 + h * 4) = wv;
    }
    __syncthreads();

    const int lane = t & 63;
    const int li   = lane & 3;
    const int gid  = lane >> 2;
    const int wid  = blockIdx.x * (blockDim.x >> 6) + (t >> 6);
    const int n0   = wid * 32 + gid * 2;
    if (n0 >= n_nodes) return;
    const bool has1 = (n0 + 1) < n_nodes;
    const int  n1   = has1 ? (n0 + 1) : n0;

    const f32x4* xp0 = (const f32x4*)(x + (size_t)n0 * DIM + li * 4);
    const f32x4* xp1 = (const f32x4*)(x + (size_t)n1 * DIM + li * 4);
    const float* wl  = wp + li * 36;   // f(li*4) = li*32 + li*4

    float acc0[9], acc1[9];
#pragma unroll
    for (int i = 0; i < 9; ++i) { acc0[i] = 0.f; acc1[i] = 0.f; }

#pragma unroll
    for (int j = 0; j < 8; ++j) {
        const f32x4 a4 = xp0[j * 4];
        const f32x4 b4 = xp1[j * 4];
#pragma unroll
        for (int k = 0; k < 4; ++k) {
            // d = j*16 + li*4 + k ; float-offset f(d) = li*36 + j*144 + k*8
            const f32x4 wa = *(const f32x4*)(wl + j * 144 + k * 8);
            const f32x4 wb = *(const f32x4*)(wl + j * 144 + k * 8 + 4);
            const float a = a4[k], bb = b4[k];
            acc0[0] += a * a;        acc1[0] += bb * bb;
            acc0[1] += a * wa[0];    acc1[1] += bb * wa[0];
            acc0[2] += a * wa[1];    acc1[2] += bb * wa[1];
            acc0[3] += a * wa[2];    acc1[3] += bb * wa[2];
            acc0[4] += a * wa[3];    acc1[4] += bb * wa[3];
            acc0[5] += a * wb[0];    acc1[5] += bb * wb[0];
            acc0[6] += a * wb[1];    acc1[6] += bb * wb[1];
            acc0[7] += a * wb[2];    acc1[7] += bb * wb[2];
            acc0[8] += a * wb[3];    acc1[8] += bb * wb[3];
        }
    }

    // 2-step butterfly within each 4-lane group (xor 1,2 -> DPP quad_perm).
#pragma unroll
    for (int i = 0; i < 9; ++i) {
        acc0[i] += __shfl_xor(acc0[i], 1, 64);
        acc0[i] += __shfl_xor(acc0[i], 2, 64);
        acc1[i] += __shfl_xor(acc1[i], 1, 64);
        acc1[i] += __shfl_xor(acc1[i], 2, 64);
    }

    // li=0 -> y[n0][0:4], li=1 -> y[n0][4:8], li=2 -> y[n1][0:4], li=3 -> y[n1][4:8]
    const bool second = (li & 1);
    const bool nodeB  = (li >= 2);

    const float sq = nodeB ? acc1[0] : acc0[0];
    const float w0 = second ? (nodeB ? acc1[5] : acc0[5]) : (nodeB ? acc1[1] : acc0[1]);
    const float w1 = second ? (nodeB ? acc1[6] : acc0[6]) : (nodeB ? acc1[2] : acc0[2]);
    const float w2 = second ? (nodeB ? acc1[7] : acc0[7]) : (nodeB ? acc1[3] : acc0[3]);
    const float w3 = second ? (nodeB ? acc1[8] : acc0[8]) : (nodeB ? acc1[4] : acc0[4]);

    float norm = fmaxf(sqrtf(sq), 1e-15f);               // MIN_NORM
    const float aa  = fminf(norm, 1.0f - 1e-6f);         // ATANH_EPS clip
    const float art = 0.5f * log1pf(2.0f * aa / (1.0f - aa));  // artanh
    const float scale = art / norm;

    const f32x4 bv4 = *(const f32x4*)b;
    f32x4 o;
    o[0] = w0 * scale + (second ? 0.f : bv4[0]);
    o[1] = w1 * scale + (second ? 0.f : bv4[1]);
    o[2] = w2 * scale + (second ? 0.f : bv4[2]);
    o[3] = w3 * scale + (second ? 0.f : bv4[3]);

    if (!(nodeB && !has1))
        *(f32x4*)(y + (size_t)n0 * 8 + li * 4) = o;
}

// 1 edge per thread, exact grid: maximum outstanding gathers (R10 lesson:
// gathers are latency-bound -> TLP is the lever). idx/out nontemporal
// (streaming; keeps the 3.2 MB y table L2-resident); y gathers plain.
__global__ __launch_bounds__(256) void edge_kernel(
    const int* __restrict__ idx, const float* __restrict__ y,
    float* __restrict__ out, int n_edges)
{
    const int e = blockIdx.x * blockDim.x + threadIdx.x;
    if (e >= n_edges) return;
    const i32x2 ii = __builtin_nontemporal_load((const i32x2*)idx + e);
    const f32x4 a0 = *(const f32x4*)(y + (size_t)ii[0] * 8);
    const f32x4 c0 = *(const f32x4*)(y + (size_t)ii[1] * 8 + 4);
    const f32x4 o0 = a0 + c0;
    __builtin_nontemporal_store(o0, (f32x4*)out + e);
}

extern "C" void kernel_launch(void* const* d_in, const int* in_sizes, int n_in,
                              void* d_out, int out_size, void* d_ws, size_t ws_size,
                              hipStream_t stream) {
    const float* x   = (const float*)d_in[0];
    const int*   idx = (const int*)d_in[1];
    const float* W   = (const float*)d_in[2];
    const float* b   = (const float*)d_in[3];
    float* out = (float*)d_out;

    const int n_nodes = in_sizes[0] / DIM;
    const int n_edges = in_sizes[1] / 2;

    float* y = (float*)d_ws;  // n_nodes * 8 floats = 3.2 MB

    // Node: 32 nodes/wave, 4 waves/block -> 128 nodes/block, single-shot.
    const int blocks1 = (n_nodes + 127) / 128;
    node_proj_kernel<<<blocks1, 256, 0, stream>>>(x, W, b, y, n_nodes);

    // Edge: 1 edge/thread, exact grid (1M threads).
    const int blocks2 = (n_edges + 255) / 256;
    edge_kernel<<<blocks2, 256, 0, stream>>>(idx, y, out, n_edges);
}